// Round 1
// baseline (387.411 us; speedup 1.0000x reference)
//
#include <hip/hip_runtime.h>
#include <hip/hip_bf16.h>
#include <math.h>

// Problem: x (2,128,512,512) f32.
//   s = sum_c x  -> (2,1,512,512)
//   e_k = conv3x3(s, sobel_k) SAME, k=0..3 ; edge = sum_k |e_k|
//   out = maxpool2x2(broadcast(edge)) -> (2,128,256,256), identical across c.
// HBM floor: 256MB read + 64MB write ~= 51us.

#define N 2
#define C 128
#define H 512
#define W 512
#define HW (H * W)
#define PH 256
#define PW 256
#define PHW (PH * PW)

// ---------------- Kernel 1: channel sum (256 MB read -> 2 MB write) --------
__global__ void __launch_bounds__(256) ksum_channels(const float* __restrict__ x,
                                                     float* __restrict__ s) {
    int idx = blockIdx.x * blockDim.x + threadIdx.x;   // 0 .. N*HW/4
    const int per_n = HW / 4;                          // float4 sites per image
    int n  = idx / per_n;
    int sp = idx % per_n;
    const float4* xp = (const float4*)(x + (size_t)n * C * HW) + sp;
    float4 acc = make_float4(0.f, 0.f, 0.f, 0.f);
#pragma unroll 8
    for (int c = 0; c < C; ++c) {
        float4 v = xp[(size_t)c * per_n];
        acc.x += v.x; acc.y += v.y; acc.z += v.z; acc.w += v.w;
    }
    ((float4*)s)[idx] = acc;
}

// ------- Kernel 2: sobel-edge + 2x2 maxpool + channel broadcast ------------
// Each thread: 4 consecutive pooled outputs (one float4) for one (n, ph),
// then writes that float4 to 16 channels (blockIdx.y selects the 16-group).
__global__ void __launch_bounds__(256) kedge_pool_bcast(const float* __restrict__ s,
                                                        float* __restrict__ out) {
    int idx = blockIdx.x * blockDim.x + threadIdx.x;   // 0 .. N*PH*(PW/4)
    const int per_n = PH * (PW / 4);
    int n   = idx / per_n;
    int r   = idx % per_n;
    int ph  = r / (PW / 4);
    int pw4 = (r % (PW / 4)) * 4;                      // base pooled column

    const float* sp = s + (size_t)n * HW;

    // s-neighborhood: rows 2ph-1 .. 2ph+2, cols 2*pw4-1 .. 2*pw4+8
    const int r0 = 2 * ph - 1;
    const int c0 = 2 * pw4 - 1;
    float v[4][10];
#pragma unroll
    for (int i = 0; i < 4; ++i) {
        int rr = r0 + i;
        bool rok = (rr >= 0) && (rr < H);
#pragma unroll
        for (int j = 0; j < 10; ++j) {
            int cc = c0 + j;
            bool ok = rok && (cc >= 0) && (cc < W);
            v[i][j] = ok ? sp[(size_t)rr * W + cc] : 0.f;
        }
    }

    float pool[4];
#pragma unroll
    for (int q = 0; q < 4; ++q) {
        float m = 0.f;   // edge >= 0, so 0 is a safe -inf substitute
#pragma unroll
        for (int a = 0; a < 2; ++a) {
#pragma unroll
            for (int b = 0; b < 2; ++b) {
                int jb = 2 * q + b;
                float p00 = v[a    ][jb], p01 = v[a    ][jb + 1], p02 = v[a    ][jb + 2];
                float p10 = v[a + 1][jb], p11 = v[a + 1][jb + 1], p12 = v[a + 1][jb + 2];
                float p20 = v[a + 2][jb], p21 = v[a + 2][jb + 1], p22 = v[a + 2][jb + 2];
                (void)p11;
                // k0 = [[-1,0,1],[-2,0,2],[-1,0,1]]
                float e0 = -p00 + p02 - 2.f * p10 + 2.f * p12 - p20 + p22;
                // k1 = [[1,2,1],[0,0,0],[-1,-2,-1]]
                float e1 =  p00 + 2.f * p01 + p02 - p20 - 2.f * p21 - p22;
                // k2 = [[2,1,0],[1,0,-1],[0,-1,-2]]
                float e2 = 2.f * p00 + p01 + p10 - p12 - p21 - 2.f * p22;
                // k3 = [[0,-1,-2],[1,0,-1],[2,1,0]]
                float e3 = -p01 - 2.f * p02 + p10 - p12 + 2.f * p20 + p21;
                float edge = fabsf(e0) + fabsf(e1) + fabsf(e2) + fabsf(e3);
                m = fmaxf(m, edge);
            }
        }
        pool[q] = m;
    }
    float4 pv = make_float4(pool[0], pool[1], pool[2], pool[3]);

    int cbase = blockIdx.y * 16;   // gridDim.y = 8 -> 128 channels
    size_t base = (size_t)n * C * PHW + (size_t)cbase * PHW + (size_t)ph * PW + pw4;
#pragma unroll
    for (int c = 0; c < 16; ++c) {
        *(float4*)(out + base + (size_t)c * PHW) = pv;
    }
}

extern "C" void kernel_launch(void* const* d_in, const int* in_sizes, int n_in,
                              void* d_out, int out_size, void* d_ws, size_t ws_size,
                              hipStream_t stream) {
    const float* x = (const float*)d_in[0];
    float* out = (float*)d_out;
    float* s   = (float*)d_ws;                 // needs N*HW*4 = 2 MB

    // Kernel 1: N*HW/4 = 131072 threads
    ksum_channels<<<dim3((N * HW / 4) / 256), dim3(256), 0, stream>>>(x, s);

    // Kernel 2: N*PH*(PW/4) = 32768 threads, y-split over 8 channel groups
    kedge_pool_bcast<<<dim3((N * PH * (PW / 4)) / 256, 8), dim3(256), 0, stream>>>(s, out);
}

// Round 2
// 380.026 us; speedup vs baseline: 1.0194x; 1.0194x over previous
//
#include <hip/hip_runtime.h>
#include <hip/hip_bf16.h>
#include <math.h>

// x (2,128,512,512) f32.
//   s = sum_c x ; edge = sum_k |conv3x3(s, sobel_k)| ; out = maxpool2x2(edge)
//   broadcast over all 128 channels.  HBM floor: 256MB rd + 64MB wr ~= 51us.
//
// Pipeline:
//   memset  : zero padded s-plane (2.1 MB)
//   k1      : partial channel sums, 4 groups of 32 ch -> 4 planes (8 MB)
//   k1b     : reduce 4 planes -> zero-padded s (stride 520, +1 row, +4 col)
//   k2      : branchless sobel+abs-sum+2x2maxpool, broadcast-store 64 MB

#define N 2
#define C 128
#define H 512
#define W 512
#define HW (H * W)
#define PH 256
#define PW 256
#define PHW (PH * PW)

#define NHW4 (N * HW / 4)          // 131072 float4 sites
#define SW 520                     // padded row stride (floats)
#define SR 514                     // padded rows
#define SPLANE (SR * SW)           // floats per padded plane

// ------------- k1: partial channel sum (4 groups x 32 channels) ------------
__global__ void __launch_bounds__(256) ksum_partial(const float* __restrict__ x,
                                                    float* __restrict__ part) {
    int idx = blockIdx.x * blockDim.x + threadIdx.x;   // 0 .. NHW4-1
    int g   = blockIdx.y;                              // channel group 0..3
    int n   = idx >> 16;                               // /65536
    int sp  = idx & 65535;
    const float4* xp = (const float4*)(x + (size_t)n * C * HW) +
                       (size_t)g * 32 * (HW / 4) + sp;
    float4 acc = make_float4(0.f, 0.f, 0.f, 0.f);
#pragma unroll 8
    for (int c = 0; c < 32; ++c) {
        float4 v = xp[(size_t)c * (HW / 4)];
        acc.x += v.x; acc.y += v.y; acc.z += v.z; acc.w += v.w;
    }
    ((float4*)part)[(size_t)g * NHW4 + idx] = acc;
}

// ------------- k1b: reduce 4 partial planes into zero-padded s -------------
__global__ void __launch_bounds__(256) kreduce_pad(const float* __restrict__ part,
                                                   float* __restrict__ spad) {
    int idx = blockIdx.x * blockDim.x + threadIdx.x;   // 0 .. NHW4-1
    int n  = idx >> 16;
    int sp = idx & 65535;
    int r  = sp / (W / 4);
    int c4 = (sp % (W / 4)) * 4;
    const float4* p = (const float4*)part;
    float4 a = p[idx];
    float4 b = p[idx + NHW4];
    float4 c = p[idx + 2 * NHW4];
    float4 d = p[idx + 3 * NHW4];
    float4 s;
    s.x = (a.x + b.x) + (c.x + d.x);
    s.y = (a.y + b.y) + (c.y + d.y);
    s.z = (a.z + b.z) + (c.z + d.z);
    s.w = (a.w + b.w) + (c.w + d.w);
    // padded position: row r -> r+1, col c -> c+4  (stride SW)
    *(float4*)(spad + (size_t)n * SPLANE + (size_t)(r + 1) * SW + (c4 + 4)) = s;
}

// ------- k2: sobel-edge + 2x2 maxpool + channel broadcast (branchless) -----
__global__ void __launch_bounds__(256) kedge_pool_bcast(const float* __restrict__ spad,
                                                        float* __restrict__ out) {
    int idx = blockIdx.x * blockDim.x + threadIdx.x;   // 0 .. N*PH*(PW/4)-1
    int n   = idx / (PH * (PW / 4));
    int r   = idx % (PH * (PW / 4));
    int ph  = r / (PW / 4);
    int pw4 = (r % (PW / 4)) * 4;

    // original s-rows 2ph-1 .. 2ph+2 -> padded rows 2ph .. 2ph+3
    // original cols 2*pw4-1 .. 2*pw4+8 -> padded cols 2*pw4+3 .. 2*pw4+12
    const float* sp = spad + (size_t)n * SPLANE + (size_t)(2 * ph) * SW + (2 * pw4 + 3);

    float v[4][10];
#pragma unroll
    for (int i = 0; i < 4; ++i)
#pragma unroll
        for (int j = 0; j < 10; ++j)
            v[i][j] = sp[(size_t)i * SW + j];

    float pool[4];
#pragma unroll
    for (int q = 0; q < 4; ++q) {
        float m = 0.f;   // edge >= 0
#pragma unroll
        for (int a = 0; a < 2; ++a) {
#pragma unroll
            for (int b = 0; b < 2; ++b) {
                int jb = 2 * q + b;
                float p00 = v[a    ][jb], p01 = v[a    ][jb + 1], p02 = v[a    ][jb + 2];
                float p10 = v[a + 1][jb],                         p12 = v[a + 1][jb + 2];
                float p20 = v[a + 2][jb], p21 = v[a + 2][jb + 1], p22 = v[a + 2][jb + 2];
                float e0 = -p00 + p02 - 2.f * p10 + 2.f * p12 - p20 + p22;
                float e1 =  p00 + 2.f * p01 + p02 - p20 - 2.f * p21 - p22;
                float e2 = 2.f * p00 + p01 + p10 - p12 - p21 - 2.f * p22;
                float e3 = -p01 - 2.f * p02 + p10 - p12 + 2.f * p20 + p21;
                float edge = fabsf(e0) + fabsf(e1) + fabsf(e2) + fabsf(e3);
                m = fmaxf(m, edge);
            }
        }
        pool[q] = m;
    }
    float4 pv = make_float4(pool[0], pool[1], pool[2], pool[3]);

    int cbase = blockIdx.y * 16;   // gridDim.y = 8 -> 128 channels
    size_t base = (size_t)n * C * PHW + (size_t)cbase * PHW + (size_t)ph * PW + pw4;
#pragma unroll
    for (int c = 0; c < 16; ++c)
        *(float4*)(out + base + (size_t)c * PHW) = pv;
}

extern "C" void kernel_launch(void* const* d_in, const int* in_sizes, int n_in,
                              void* d_out, int out_size, void* d_ws, size_t ws_size,
                              hipStream_t stream) {
    const float* x = (const float*)d_in[0];
    float* out  = (float*)d_out;
    float* part = (float*)d_ws;                                  // 4*N*HW*4 = 8 MB
    float* spad = (float*)((char*)d_ws + (size_t)8 * 1024 * 1024); // N*SPLANE*4 ~= 2.14 MB

    // zero the padded s-plane (borders must be 0; ws is poisoned each launch)
    hipMemsetAsync(spad, 0, (size_t)N * SPLANE * sizeof(float), stream);

    // k1: 2048 blocks (8/CU): 256 MB read, 8 MB write
    ksum_partial<<<dim3(NHW4 / 256, 4), dim3(256), 0, stream>>>(x, part);

    // k1b: 8 MB read, 2 MB write into padded plane
    kreduce_pad<<<dim3(NHW4 / 256), dim3(256), 0, stream>>>(part, spad);

    // k2: cached reads, 64 MB coalesced write
    kedge_pool_bcast<<<dim3((N * PH * (PW / 4)) / 256, 8), dim3(256), 0, stream>>>(spad, out);
}